// Round 10
// baseline (1068.872 us; speedup 1.0000x reference)
//
#include <hip/hip_runtime.h>

#define NEGV (-10000.0f)

constexpr int Bb = 512;
constexpr int Ss = 1024;
constexpr int Tt = 64;

// row_ror:1 DPP (dpp_ctrl 0x121): cyclic rotate within each 16-lane row.
// Direction is NOT assumed anywhere: trow preload simulates the same chain,
// and the decode constant d is probed at runtime.
__device__ __forceinline__ float dpp_ror1_f(float x) {
    return __int_as_float(__builtin_amdgcn_update_dpp(
        0, __float_as_int(x), 0x121, 0xF, 0xF, false));
}
__device__ __forceinline__ int dpp_ror1_i(int x) {
    return __builtin_amdgcn_update_dpp(0, x, 0x121, 0xF, 0xF, false);
}

// One wave (64 lanes) per batch. Lane n owns next-tag n and trans[n][*] in
// 64 VGPRs. fv values tour lanes via 3 shuffles (xor16/32/48) + 15 DPP
// rotations per phase. No barriers, no LDS on the recurrence critical path.
__global__ __launch_bounds__(64, 1) void viterbi_wave(
    const float* __restrict__ feats,      // [B,S,T]
    const float* __restrict__ trans,      // [T,T] (next, prev)
    float* __restrict__ path_score,       // [B]
    float* __restrict__ best_path)        // [B,S] tags as float
{
    __shared__ unsigned char bp_lds[Ss][Tt];   // 64 KB (first 16 KB doubles as T_lds in preload)
    __shared__ unsigned char ccomp[32][Tt];    // 2 KB  composed chunk jumps
    __shared__ int btags[32];                  // 128 B

    const int b    = blockIdx.x;
    const int lane = threadIdx.x;
    const float* fb = feats + (size_t)b * (Ss * Tt);

    // ---- preload: stage trans into LDS (aliased with bp rows 0..255) ----
    float* T_lds = (float*)&bp_lds[0][0];
    {
        float4*       dst = (float4*)T_lds;
        const float4* src = (const float4*)trans;
#pragma unroll
        for (int i = 0; i < 16; ++i) dst[i * 64 + lane] = src[i * 64 + lane];
    }
    __syncthreads();

    // trow[r*16+k] = trans[lane][px_{r,k}] where px follows the EXACT same
    // shuffle/rotation schedule the main loop applies to fv.
    float trow[64];
#pragma unroll
    for (int r = 0; r < 4; ++r) {
        int px = lane ^ (r << 4);              // phase base: __shfl(fv, lane^16r)
#pragma unroll
        for (int k = 0; k < 16; ++k) {
            trow[r * 16 + k] = T_lds[lane * 64 + px];
            px = dpp_ror1_i(px);
        }
    }
    // probe rotation direction: low4(px) advances by d each ror1 step
    int d;
    {
        int p1 = dpp_ror1_i(lane);
        d = (p1 - lane) & 15;
    }
    float tend = trans[63 * Tt + lane];        // terminal row (END_IX = 63)
    __syncthreads();                            // T_lds reads done before bp writes

    float fv  = (lane == 62) ? 0.0f : NEGV;    // START_IX = 62
    int  comp = lane;
    float f0 = fb[lane];                        // feat s
    float f1 = fb[Tt + lane];                   // feat s+1

#define PHASE(R, XR, MR, KR)                                        \
    {                                                               \
        float xr = XR;                                              \
        MR = xr + trow[(R) * 16];                                   \
        KR = (R) * 16;                                              \
        _Pragma("unroll")                                           \
        for (int k = (R) * 16 + 1; k < (R) * 16 + 16; ++k) {        \
            xr = dpp_ror1_f(xr);                                    \
            float c = xr + trow[k];                                 \
            if (c > MR) { MR = c; KR = k; }                         \
        }                                                           \
    }

    for (int s = 0; s < Ss; ++s) {
        int sp = s + 2; sp = sp < Ss ? sp : Ss - 1;
        float f2 = fb[(size_t)sp * Tt + lane];  // prefetch feat s+2

        float x0 = fv;
        float x1 = __shfl(fv, lane ^ 16);
        float x2 = __shfl(fv, lane ^ 32);
        float x3 = __shfl(fv, lane ^ 48);

        float m0, m1, m2, m3; int k0, k1, k2, k3;
        PHASE(0, x0, m0, k0)
        PHASE(1, x1, m1, k1)
        PHASE(2, x2, m2, k2)
        PHASE(3, x3, m3, k3)

        float m = m0; int kk = k0;
        if (m1 > m) { m = m1; kk = k1; }
        if (m2 > m) { m = m2; kk = k2; }
        if (m3 > m) { m = m3; kk = k3; }

        // decode argmax prev: low4 advanced d per rotation, high2 = lane^phase
        int p = ((lane + d * (kk & 15)) & 15) | ((lane ^ kk) & 48);

        bp_lds[s][lane] = (unsigned char)p;
        comp = __shfl(comp, p);
        if ((s & 31) == 31) { ccomp[s >> 5][lane] = (unsigned char)comp; comp = lane; }

        fv = m + f0;
        f0 = f1; f1 = f2;
    }
#undef PHASE

    // Terminal: fv + trans[END][lane]; wave argmax (tie -> lower index).
    float mr = fv + tend; int ir = lane;
#pragma unroll
    for (int off = 32; off >= 1; off >>= 1) {
        float mo = __shfl_xor(mr, off);
        int   io = __shfl_xor(ir, off);
        bool take = (mo > mr) || ((mo == mr) && (io < ir));
        mr = take ? mo : mr; ir = take ? io : ir;
    }
    if (lane == 0) {
        path_score[b] = mr;
        int tag = ir;
        for (int c2 = 31; c2 >= 0; --c2) {      // serial chunk-tag chase in LDS
            btags[c2] = tag;
            tag = ccomp[c2][tag];
        }
    }
    __syncthreads();

    // Parallel in-chunk backtrace: lane c handles steps [32c, 32c+32).
    if (lane < 32) {
        int tag = btags[lane];
        float* op = best_path + (size_t)b * Ss + lane * 32;
        for (int i = 31; i >= 0; --i) {
            op[i] = (float)tag;
            tag = bp_lds[lane * 32 + i][tag];
        }
    }
}

extern "C" void kernel_launch(void* const* d_in, const int* in_sizes, int n_in,
                              void* d_out, int out_size, void* d_ws, size_t ws_size,
                              hipStream_t stream) {
    const float* feats = (const float*)d_in[0];   // [512,1024,64] f32
    const float* trans = (const float*)d_in[1];   // [64,64] f32

    float* path_score = (float*)d_out;            // [512]
    float* best_path  = (float*)d_out + Bb;       // [512,1024] tags as float

    viterbi_wave<<<Bb, 64, 0, stream>>>(feats, trans, path_score, best_path);
}